// Round 1
// baseline (287.707 us; speedup 1.0000x reference)
//
#include <hip/hip_runtime.h>
#include <math.h>

// tau(k) = 3.9 * kL^(-2/3) / sqrt( 2F1(1/3, 17/6, 4/3, -kL^-2) ),  kL = 0.59*|k|
// Work in q = kL^2.  Branch A (q >= 1/phi): (1+t)^(-1/3) * 2F1(1/3,-3/2,4/3, 1/(1+q))
// Branch B (q <  1/phi): A*q^(1/3) + B*q^(17/6) * 2F1(17/6,5/2,7/2, -q)
// B = Gamma(4/3)Gamma(-5/2)/(Gamma(1/3)Gamma(-3/2)) = (1/3)*(-2/5) = -2/15 exactly.

#define NT 28  // 0.618^28 ~ 2e-6 relative tail; threshold allows ~2e-3

__host__ __device__ constexpr float coefA(int n) {
    // a=1/3, b=-3/2, c=4/3:  (a+n)(b+n)/((c+n)(n+1))
    return (float)(((1.0/3.0 + n) * (n - 1.5)) / ((4.0/3.0 + n) * (n + 1.0)));
}
__host__ __device__ constexpr float coefB(int n) {
    // a=17/6, b=5/2, c=7/2
    return (float)(((17.0/6.0 + n) * (n + 2.5)) / ((3.5 + n) * (n + 1.0)));
}

__global__ __launch_bounds__(256) void mann_elt_kernel(
        const float* __restrict__ k, float* __restrict__ out, int n_quads) {
    int tid = blockIdx.x * blockDim.x + threadIdx.x;
    if (tid >= n_quads) return;

    // 4 elements per thread: 12 contiguous floats = 3 float4 loads, all bytes used.
    const float4* __restrict__ k4 = (const float4*)k;
    float4 v0 = k4[3*tid+0];
    float4 v1 = k4[3*tid+1];
    float4 v2 = k4[3*tid+2];

    const float LS2 = 0.3481f;  // 0.59^2
    float q[4];
    q[0] = LS2 * (v0.x*v0.x + v0.y*v0.y + v0.z*v0.z);
    q[1] = LS2 * (v0.w*v0.w + v1.x*v1.x + v1.y*v1.y);
    q[2] = LS2 * (v1.z*v1.z + v1.w*v1.w + v2.x*v2.x);
    q[3] = LS2 * (v2.y*v2.y + v2.z*v2.z + v2.w*v2.w);

    bool brA[4];
    float z[4], acc[4];
    #pragma unroll
    for (int e = 0; e < 4; ++e) {
        brA[e] = q[e] >= 0.6180339887f;  // t = 1/q <= phi
        float r = 1.0f / (1.0f + q[e]);  // = t/(1+t)
        z[e] = brA[e] ? r : -q[e];
        acc[e] = 1.0f;
    }

    // Unified Horner for both branches; coefficients are compile-time literals,
    // per-lane selected (cndmask) -> no divergent loop, 4 independent dep-chains.
    #pragma unroll
    for (int n = NT - 1; n >= 0; --n) {
        const float cA = coefA(n);
        const float cB = coefB(n);
        #pragma unroll
        for (int e = 0; e < 4; ++e) {
            float c = brA[e] ? cA : cB;
            acc[e] = fmaf(c * z[e], acc[e], 1.0f);
        }
    }

    float res[4];
    #pragma unroll
    for (int e = 0; e < 4; ++e) {
        float Lk  = log2f(q[e]);                    // log2(kL^2)
        float p13 = exp2f(Lk * (1.0f/3.0f));        // q^(1/3) = t^(-1/3)
        // Branch B: f = A*q^(1/3) + B*q^(17/6)*S
        float fB  = fmaf((-2.0f/15.0f) * exp2f(Lk * (17.0f/6.0f)), acc[e],
                         0.68834394f * p13);
        // Branch A: f = (q/(1+q))^(1/3) * S
        float L1p = log2f(1.0f + q[e]);
        float fA  = exp2f((Lk - L1p) * (1.0f/3.0f)) * acc[e];
        float f   = brA[e] ? fA : fB;
        // out = 3.9 * q^(-1/3) / sqrt(f)
        res[e] = 3.9f * rsqrtf(f) / p13;
    }

    ((float4*)out)[tid] = make_float4(res[0], res[1], res[2], res[3]);
}

extern "C" void kernel_launch(void* const* d_in, const int* in_sizes, int n_in,
                              void* d_out, int out_size, void* d_ws, size_t ws_size,
                              hipStream_t stream) {
    const float* k = (const float*)d_in[0];
    float* out = (float*)d_out;
    int n_quads = out_size / 4;                 // 16,777,216 / 4 = 4,194,304
    int threads = 256;
    int blocks = (n_quads + threads - 1) / threads;  // 16384
    mann_elt_kernel<<<blocks, threads, 0, stream>>>(k, out, n_quads);
}

// Round 2
// 286.048 us; speedup vs baseline: 1.0058x; 1.0058x over previous
//
#include <hip/hip_runtime.h>
#include <math.h>

// tau(k) = 3.9 * kL^(-2/3) / sqrt( 2F1(1/3, 17/6, 4/3, -kL^-2) ),  kL = 0.59*|k|
// q = kL^2.  Fold q^(-1/3) into the rsqrt argument (out = 3.9*rsqrt(arg)):
//   Branch A (q >= 1/phi): arg = q * r^(1/3) * S_A,  r = 1/(1+q), S_A = 2F1(1/3,-3/2,4/3, r)
//   Branch B (q <  1/phi): arg = A*q + B*q^(7/2)*S_B, S_B = 2F1(17/6,5/2,7/2, -q)
//     q^(7/2) = q^3 * sqrt(q);  B = -2/15 exact;  A = 0.68834394
// Series args bounded by 1/phi = 0.618 -> NT=12 gives ~6e-4 relative tail.

#define NT 12

__host__ __device__ constexpr float coefA(int n) {
    // a=1/3, b=-3/2, c=4/3:  (a+n)(b+n)/((c+n)(n+1))
    return (float)(((1.0/3.0 + n) * (n - 1.5)) / ((4.0/3.0 + n) * (n + 1.0)));
}
__host__ __device__ constexpr float coefB(int n) {
    // a=17/6, b=5/2, c=7/2
    return (float)(((17.0/6.0 + n) * (n + 2.5)) / ((3.5 + n) * (n + 1.0)));
}

__device__ __forceinline__ float frcp(float x)   { return __builtin_amdgcn_rcpf(x); }
__device__ __forceinline__ float frsq(float x)   { return __builtin_amdgcn_rsqf(x); }
__device__ __forceinline__ float fsqrt_(float x) { return __builtin_amdgcn_sqrtf(x); }
#if __has_builtin(__builtin_amdgcn_logf)
__device__ __forceinline__ float flog2(float x)  { return __builtin_amdgcn_logf(x); }
#else
__device__ __forceinline__ float flog2(float x)  { return __log2f(x); }
#endif
#if __has_builtin(__builtin_amdgcn_exp2f)
__device__ __forceinline__ float fexp2(float x)  { return __builtin_amdgcn_exp2f(x); }
#else
__device__ __forceinline__ float fexp2(float x)  { return exp2f(x); }
#endif

__global__ __launch_bounds__(256) void mann_elt_kernel(
        const float* __restrict__ k, float* __restrict__ out, int n_quads) {
    int tid = blockIdx.x * blockDim.x + threadIdx.x;
    if (tid >= n_quads) return;

    // 4 elements per thread: 12 contiguous floats = 3 float4 loads, all bytes used.
    const float4* __restrict__ k4 = (const float4*)k;
    float4 v0 = k4[3*tid+0];
    float4 v1 = k4[3*tid+1];
    float4 v2 = k4[3*tid+2];

    const float LS2 = 0.3481f;  // 0.59^2
    float q[4];
    q[0] = LS2 * (v0.x*v0.x + v0.y*v0.y + v0.z*v0.z);
    q[1] = LS2 * (v0.w*v0.w + v1.x*v1.x + v1.y*v1.y);
    q[2] = LS2 * (v1.z*v1.z + v1.w*v1.w + v2.x*v2.x);
    q[3] = LS2 * (v2.y*v2.y + v2.z*v2.z + v2.w*v2.w);

    bool brA[4];
    float z[4], acc[4], rr[4];
    #pragma unroll
    for (int e = 0; e < 4; ++e) {
        brA[e] = q[e] >= 0.6180339887f;      // t = 1/q <= phi
        rr[e] = frcp(1.0f + q[e]);           // = t/(1+t), series arg for branch A
        z[e] = brA[e] ? rr[e] : -q[e];
        acc[e] = 1.0f;
    }

    // Unified Horner; coefficients are compile-time literals, per-lane selected
    // (v_cndmask) -> no divergent loop; 4 independent dependency chains.
    #pragma unroll
    for (int n = NT - 1; n >= 0; --n) {
        const float cA = coefA(n);
        const float cB = coefB(n);
        #pragma unroll
        for (int e = 0; e < 4; ++e) {
            float c = brA[e] ? cA : cB;
            acc[e] = fmaf(c * z[e], acc[e], 1.0f);
        }
    }

    float res[4];
    #pragma unroll
    for (int e = 0; e < 4; ++e) {
        float qq = q[e];
        float S  = acc[e];
        // Branch A: arg = q * r^(1/3) * S   (r^(1/3) via native log2/exp2)
        float cr   = fexp2(flog2(rr[e]) * (1.0f/3.0f));
        float argA = qq * cr * S;
        // Branch B: arg = A*q + B*q^3*sqrt(q)*S   (no log/exp needed)
        float q72  = qq * qq * qq * fsqrt_(qq);
        float argB = fmaf((-2.0f/15.0f) * q72, S, 0.68834394f * qq);
        float arg  = brA[e] ? argA : argB;
        res[e] = 3.9f * frsq(arg);
    }

    ((float4*)out)[tid] = make_float4(res[0], res[1], res[2], res[3]);
}

extern "C" void kernel_launch(void* const* d_in, const int* in_sizes, int n_in,
                              void* d_out, int out_size, void* d_ws, size_t ws_size,
                              hipStream_t stream) {
    const float* k = (const float*)d_in[0];
    float* out = (float*)d_out;
    int n_quads = out_size / 4;                 // 16,777,216 / 4 = 4,194,304
    int threads = 256;
    int blocks = (n_quads + threads - 1) / threads;  // 16384
    mann_elt_kernel<<<blocks, threads, 0, stream>>>(k, out, n_quads);
}